// Round 8
// baseline (171.410 us; speedup 1.0000x reference)
//
#include <hip/hip_runtime.h>
#include <hip/hip_bf16.h>
#include <math.h>

typedef __bf16 bf16;
typedef __attribute__((ext_vector_type(8))) __bf16 bf16x8;
typedef __attribute__((ext_vector_type(4))) __bf16 bf16x4;
typedef __attribute__((ext_vector_type(4))) float f32x4;
typedef __attribute__((ext_vector_type(16))) float f32x16;

#define MFMA16(a, b, c) __builtin_amdgcn_mfma_f32_16x16x32_bf16((a), (b), (c), 0, 0, 0)
#define MFMA32(a, b, c) __builtin_amdgcn_mfma_f32_32x32x16_bf16((a), (b), (c), 0, 0, 0)

// async global->LDS, 16B per lane (wave-uniform LDS base + lane*16)
__device__ __forceinline__ void glds16(const bf16* g, bf16* l) {
  __builtin_amdgcn_global_load_lds(
      (const __attribute__((address_space(1))) unsigned int*)g,
      (__attribute__((address_space(3))) unsigned int*)l, 16, 0, 0);
}

// Problem dims
// B=32, T=1024, VOCAB=512, RANK=256
// x [32768, 512] f32 ; W_attn [512,768] ; b_attn[768] ; W_proj [256,512] ; b_proj[512]

// ---------------- weight convert+transpose (tiny) ----------------
__global__ __launch_bounds__(256) void cvt_wattn(const float* __restrict__ w,
                                                 bf16* __restrict__ wt) {
  int o = blockIdx.x * 256 + threadIdx.x;   // 768*512 = 393216
  int n = o >> 9, kk = o & 511;
  wt[o] = (bf16)w[kk * 768 + n];            // WT[n][k] = W[k][n]
}

__global__ __launch_bounds__(256) void cvt_wproj(const float* __restrict__ w,
                                                 bf16* __restrict__ wt) {
  int o = blockIdx.x * 256 + threadIdx.x;   // 512*256 = 131072
  int n = o >> 8, kk = o & 255;
  wt[o] = (bf16)w[kk * 512 + n];            // WT[n][k] = W[k][n]
}

// ---------------- x f32 -> bf16 (streamed, BW-bound) ----------------
__global__ __launch_bounds__(256) void cvt_x(const float* __restrict__ x,
                                             bf16* __restrict__ xb) {
  size_t i = ((size_t)blockIdx.x * 256 + threadIdx.x) * 8;
  f32x4 f0 = *(const f32x4*)(x + i);
  f32x4 f1 = *(const f32x4*)(x + i + 4);
  bf16x8 h;
#pragma unroll
  for (int e = 0; e < 4; ++e) { h[e] = (bf16)f0[e]; h[e + 4] = (bf16)f1[e]; }
  *(bf16x8*)(xb + i) = h;
}

// ---------------- qkv GEMM: [32768,512]bf16 x [768,512]^T ----------------
// v7: m97 structure + SWAPPED MFMA (W on A side) -> acc regs span output
// columns -> bf16x4 vector epilogue stores. XCD-chunked grid.
__global__ __launch_bounds__(256) void gemm_qkv(
    const bf16* __restrict__ xb, const bf16* __restrict__ WT,
    const float* __restrict__ b_attn,
    bf16* __restrict__ qo, bf16* __restrict__ ko, bf16* __restrict__ vo) {
  __shared__ __attribute__((aligned(16))) bf16 As[128][32];
  __shared__ __attribute__((aligned(16))) bf16 Bs[128][32];
  const int tid = threadIdx.x;
  const int id = blockIdx.x;
  const int xcd = id & 7;
  const int rest = id >> 3;          // 0..191
  const int bmL = rest / 6;          // 0..31
  const int bn = (rest % 6) * 128;
  const int bm = (xcd * 32 + bmL) * 128;
  const int lane = tid & 63, wid = tid >> 6;
  const int l15 = lane & 15, lg = lane >> 4;
  const int wm = (wid >> 1) * 64, wn = (wid & 1) * 64;

  f32x4 acc[4][4] = {};

  const int ar = tid >> 2;
  const int ac = (tid & 3) * 8;
  const bf16* aB = xb + (size_t)bm * 512 + (size_t)ar * 512 + ac;
  const bf16* bB = WT + (size_t)bn * 512 + (size_t)ar * 512 + ac;
  bf16* As0 = &As[0][0];
  bf16* Bs0 = &Bs[0][0];

  for (int kt = 0; kt < 16; ++kt) {
    const int k0 = kt * 32;
    glds16(aB + k0,            As0 + (size_t)tid * 8);
    glds16(aB + 64 * 512 + k0, As0 + (size_t)(256 + tid) * 8);
    glds16(bB + k0,            Bs0 + (size_t)tid * 8);
    glds16(bB + 64 * 512 + k0, Bs0 + (size_t)(256 + tid) * 8);
    __syncthreads();   // drains vmcnt -> tiles ready
    bf16x8 af[4], bfr[4];
#pragma unroll
    for (int mi = 0; mi < 4; ++mi)
      af[mi] = *(const bf16x8*)&As[wm + mi * 16 + l15][lg * 8];
#pragma unroll
    for (int ni = 0; ni < 4; ++ni)
      bfr[ni] = *(const bf16x8*)&Bs[wn + ni * 16 + l15][lg * 8];
#pragma unroll
    for (int mi = 0; mi < 4; ++mi)
#pragma unroll
      for (int ni = 0; ni < 4; ++ni)
        acc[mi][ni] = MFMA16(bfr[ni], af[mi], acc[mi][ni]);
    __syncthreads();
  }

#pragma unroll
  for (int ni = 0; ni < 4; ++ni) {
    int gc0 = bn + wn + ni * 16 + lg * 4;
    f32x4 bias = *(const f32x4*)(b_attn + gc0);
    int seg = gc0 >> 8;        // 0=q 1=k 2=v (4-vector never crosses 256)
    int cc = gc0 & 255;
    bf16* op = (seg == 0) ? qo : ((seg == 1) ? ko : vo);
#pragma unroll
    for (int mi = 0; mi < 4; ++mi) {
      int gr = bm + wm + mi * 16 + l15;
      bf16x4 pk;
#pragma unroll
      for (int r = 0; r < 4; ++r) pk[r] = (bf16)(acc[mi][ni][r] + bias[r]);
      *(bf16x4*)(op + (size_t)gr * 256 + cc) = pk;
    }
  }
}

// ---------------- v -> v^T : [32][1024][256] -> [32][256][1024] ----------------
__global__ __launch_bounds__(256) void transpose_v(const bf16* __restrict__ v,
                                                   bf16* __restrict__ vt) {
  __shared__ bf16 tile[32][33];
  const int b = blockIdx.z;
  const int t0 = blockIdx.x * 32;
  const int d0 = blockIdx.y * 32;
  const int tid = threadIdx.x;
  const int r = tid >> 3, c4 = (tid & 7) * 4;
  bf16x4 in = *(const bf16x4*)(v + (size_t)(b * 1024 + t0 + r) * 256 + d0 + c4);
  tile[r][c4] = in[0]; tile[r][c4 + 1] = in[1];
  tile[r][c4 + 2] = in[2]; tile[r][c4 + 3] = in[3];
  __syncthreads();
  bf16x4 o;
  o[0] = tile[c4][r]; o[1] = tile[c4 + 1][r];
  o[2] = tile[c4 + 2][r]; o[3] = tile[c4 + 3][r];
  *(bf16x4*)(vt + (size_t)(b * 256 + d0 + r) * 1024 + t0 + c4) = o;
}

// ---------------- flash attention, causal, scale 1/16 ----------------
// v8: 4 waves x 32 q-rows via mfma_32x32x16 (halves per-CU LDS read traffic);
// K/Vt double-buffered in LDS via global_load_lds with XOR-swizzle
// (inverse-swizzled global source + swizzled read, linear LDS dest);
// ONE barrier per tile; lane-local softmax (q = lane&31, one shfl_xor(32)).
__global__ __launch_bounds__(256, 1) void attn_fwd(
    const bf16* __restrict__ q, const bf16* __restrict__ k,
    const bf16* __restrict__ vt, bf16* __restrict__ y) {
  __shared__ __attribute__((aligned(16))) bf16 Ks[2][64 * 256];   // 512B rows, swz
  __shared__ __attribute__((aligned(16))) bf16 Vts[2][256 * 64];  // 128B rows, swz
  __shared__ __attribute__((aligned(16))) bf16 Ps[4][32][68];     // per-wave P, +4 pad
  const int tid = threadIdx.x, lane = tid & 63, wid = tid >> 6;
  const int l31 = lane & 31, hi = lane >> 5;

  // 256 blocks: id = xcd + 8*(qt + 8*bg); batch = xcd + 8*bg
  const int id = blockIdx.x;
  const int xcd = id & 7, rest = id >> 3;
  const int qt = rest & 7, bg = rest >> 3;
  const int b = xcd + 8 * bg;
  const int q0 = qt * 128 + wid * 32;    // this wave's 32 q-rows

  // Q B-frags: qf[ds] -> q = q0+l31, d = ds*16 + hi*8 + j
  bf16x8 qf[16];
  {
    const bf16* qp = q + (size_t)(b * 1024 + q0 + l31) * 256 + hi * 8;
#pragma unroll
    for (int ds = 0; ds < 16; ++ds) qf[ds] = *(const bf16x8*)(qp + ds * 16);
  }
  f32x16 o[8] = {};     // o[db]: q = l31, d = db*32 + (r&3) + 8*(r>>2) + 4*hi
  float m_st = -1e30f;  // running max for q = q0+l31 (replicated hi/lo)
  float l_st = 0.f;     // running denom

  const char* kbase = (const char*)(k + (size_t)b * 1024 * 256);
  const char* vtbase = (const char*)(vt + (size_t)b * 256 * 1024);
  // staging maps: LDS linear dest (i*256+tid)*16B; swizzle applied on SOURCE
  const int kr0 = tid >> 5;          // K row mod 8 == kr0 (issues step by 8)
  const int ku = (tid & 31) * 16;    // byte col in 512B row
  const int ksz = kr0 << 4;
  const int vr0 = tid >> 3;          // Vt rows step by 32 -> row&7 == vr0&7
  const int vu = (tid & 7) * 16;     // byte col in 128B row
  const int vsz = (vr0 & 7) << 4;

  const int ntiles = 2 * qt + 2;

  // prologue: stage tile 0 into buffer 0
#pragma unroll
  for (int i = 0; i < 8; ++i)
    glds16((const bf16*)(kbase + (size_t)(kr0 + i * 8) * 512 + (ku ^ ksz)),
           &Ks[0][0] + ((size_t)i * 256 + tid) * 8);
#pragma unroll
  for (int i = 0; i < 8; ++i)
    glds16((const bf16*)(vtbase + (size_t)(vr0 + i * 32) * 2048 + (vu ^ vsz)),
           &Vts[0][0] + ((size_t)i * 256 + tid) * 8);
  __syncthreads();

  int cur = 0;
  for (int tt = 0; tt < ntiles; ++tt) {
    const int kv0 = tt * 64;
    if (tt + 1 < ntiles) {     // stage next tile; drains under compute below
      const int kvn = kv0 + 64;
      const int nxt = cur ^ 1;
#pragma unroll
      for (int i = 0; i < 8; ++i)
        glds16((const bf16*)(kbase + (size_t)(kvn + kr0 + i * 8) * 512 + (ku ^ ksz)),
               &Ks[nxt][0] + ((size_t)i * 256 + tid) * 8);
#pragma unroll
      for (int i = 0; i < 8; ++i)
        glds16((const bf16*)(vtbase + (size_t)(vr0 + i * 32) * 2048 + kvn * 2 + (vu ^ vsz)),
               &Vts[nxt][0] + ((size_t)i * 256 + tid) * 8);
    }

    // S^T = K Q^T : A = K rows (s on lanes l31, 2 blocks), B = Q (q on lanes)
    const char* kc = (const char*)&Ks[cur][0];
    f32x16 st[2] = {};
    __builtin_amdgcn_s_setprio(1);
#pragma unroll
    for (int sb = 0; sb < 2; ++sb) {
      const int row0 = sb * 32 + l31;
      const char* rp = kc + (size_t)row0 * 512;
      const int sw = (row0 & 7) << 4;
#pragma unroll
      for (int ds = 0; ds < 16; ++ds) {
        bf16x8 kf = *(const bf16x8*)(rp + ((ds * 32 + hi * 16) ^ sw));
        st[sb] = MFMA32(kf, qf[ds], st[sb]);
      }
    }
    __builtin_amdgcn_s_setprio(0);

    // scale + causal mask; lane's 32 values all belong to q = q0+l31
    const int qg = q0 + l31;
    float tmax = -1e30f;
#pragma unroll
    for (int sb = 0; sb < 2; ++sb)
#pragma unroll
      for (int r = 0; r < 16; ++r) {
        int sg = kv0 + sb * 32 + (r & 3) + 8 * (r >> 2) + 4 * hi;
        float v = st[sb][r] * 0.0625f;
        v = (sg > qg) ? -1e30f : v;
        st[sb][r] = v;
        tmax = fmaxf(tmax, v);
      }
    tmax = fmaxf(tmax, __shfl_xor(tmax, 32, 64));   // hi/lo halves combine

    // defer-max: only rescale when the tile max grew past THR=8
    if (!__all(tmax <= m_st + 8.f)) {
      float mnew = fmaxf(m_st, tmax);
      float corr = __expf(m_st - mnew);
      m_st = mnew; l_st *= corr;
#pragma unroll
      for (int db = 0; db < 8; ++db)
#pragma unroll
        for (int r = 0; r < 16; ++r) o[db][r] *= corr;
    }

    // P = exp(S - m): pack bf16x4 runs (s = sb*32 + rb*8 + hi*4 + j)
    float rsum = 0.f;
#pragma unroll
    for (int sb = 0; sb < 2; ++sb)
#pragma unroll
      for (int rb = 0; rb < 4; ++rb) {
        bf16x4 pk;
#pragma unroll
        for (int j = 0; j < 4; ++j) {
          float p = __expf(st[sb][rb * 4 + j] - m_st);
          rsum += p;
          pk[j] = (bf16)p;
        }
        *(bf16x4*)&Ps[wid][l31][sb * 32 + rb * 8 + hi * 4] = pk;
      }
    rsum += __shfl_xor(rsum, 32, 64);
    l_st += rsum;

    // PV : A = Vt rows (d on lanes, 8 blocks), B = P (q on lanes, k=s)
    const char* vc = (const char*)&Vts[cur][0];
    __builtin_amdgcn_s_setprio(1);
#pragma unroll
    for (int db = 0; db < 8; ++db) {
      const int row0 = db * 32 + l31;
      const char* rp = vc + (size_t)row0 * 128;
      const int sw = (row0 & 7) << 4;
#pragma unroll
      for (int ss = 0; ss < 4; ++ss) {
        bf16x8 vf = *(const bf16x8*)(rp + ((ss * 32 + hi * 16) ^ sw));
        bf16x8 pf = *(const bf16x8*)&Ps[wid][l31][ss * 16 + hi * 8];
        o[db] = MFMA32(vf, pf, o[db]);
      }
    }
    __builtin_amdgcn_s_setprio(0);

    __syncthreads();   // all reads of cur done + next-buffer glds drained
    cur ^= 1;
  }

  // epilogue: lane-local q; bf16x4 stores along d
  float inv = 1.f / l_st;
  bf16* yp = y + (size_t)(b * 1024 + q0 + l31) * 256;
#pragma unroll
  for (int db = 0; db < 8; ++db)
#pragma unroll
    for (int rb = 0; rb < 4; ++rb) {
      bf16x4 pk;
#pragma unroll
      for (int j = 0; j < 4; ++j) pk[j] = (bf16)(o[db][rb * 4 + j] * inv);
      *(bf16x4*)(yp + db * 32 + rb * 8 + hi * 4) = pk;
    }
}

// ---------------- proj GEMM + bias + GELU (tanh form) ----------------
// v7: swapped MFMA -> f32x4 vector stores; erff -> overflow-safe tanh GELU.
__global__ __launch_bounds__(256) void gemm_proj(
    const bf16* __restrict__ y, const bf16* __restrict__ WT,
    const float* __restrict__ b_proj, float* __restrict__ out) {
  __shared__ __attribute__((aligned(16))) bf16 As[128][32];
  __shared__ __attribute__((aligned(16))) bf16 Bs[128][32];
  const int tid = threadIdx.x;
  const int id = blockIdx.x;
  const int xcd = id & 7;
  const int rest = id >> 3;          // 0..127
  const int bmL = rest >> 2;         // 0..31
  const int bn = (rest & 3) * 128;
  const int bm = (xcd * 32 + bmL) * 128;
  const int lane = tid & 63, wid = tid >> 6;
  const int l15 = lane & 15, lg = lane >> 4;
  const int wm = (wid >> 1) * 64, wn = (wid & 1) * 64;
  f32x4 acc[4][4] = {};

  const int ar = tid >> 2;
  const int ac = (tid & 3) * 8;
  const bf16* aB = y + (size_t)bm * 256 + (size_t)ar * 256 + ac;
  const bf16* bB = WT + (size_t)bn * 256 + (size_t)ar * 256 + ac;
  bf16* As0 = &As[0][0];
  bf16* Bs0 = &Bs[0][0];

  for (int kt = 0; kt < 8; ++kt) {
    const int k0 = kt * 32;
    glds16(aB + k0,            As0 + (size_t)tid * 8);
    glds16(aB + 64 * 256 + k0, As0 + (size_t)(256 + tid) * 8);
    glds16(bB + k0,            Bs0 + (size_t)tid * 8);
    glds16(bB + 64 * 256 + k0, Bs0 + (size_t)(256 + tid) * 8);
    __syncthreads();
    bf16x8 af[4], bfr[4];
#pragma unroll
    for (int mi = 0; mi < 4; ++mi)
      af[mi] = *(const bf16x8*)&As[wm + mi * 16 + l15][lg * 8];
#pragma unroll
    for (int ni = 0; ni < 4; ++ni)
      bfr[ni] = *(const bf16x8*)&Bs[wn + ni * 16 + l15][lg * 8];
#pragma unroll
    for (int mi = 0; mi < 4; ++mi)
#pragma unroll
      for (int ni = 0; ni < 4; ++ni)
        acc[mi][ni] = MFMA16(bfr[ni], af[mi], acc[mi][ni]);
    __syncthreads();
  }

#pragma unroll
  for (int ni = 0; ni < 4; ++ni) {
    int gc0 = bn + wn + ni * 16 + lg * 4;
    f32x4 bias = *(const f32x4*)(b_proj + gc0);
#pragma unroll
    for (int mi = 0; mi < 4; ++mi) {
      int gr = bm + wm + mi * 16 + l15;
      f32x4 g;
#pragma unroll
      for (int r = 0; r < 4; ++r) {
        float v = acc[mi][ni][r] + bias[r];
        float z = 1.5957691216f * (v + 0.044715f * v * v * v);
        float t = __expf(z);
        float th = 1.f - 2.f / (t + 1.f);
        g[r] = 0.5f * v * (1.f + th);
      }
      *(f32x4*)(out + (size_t)gr * 512 + gc0) = g;
    }
  }
}

extern "C" void kernel_launch(void* const* d_in, const int* in_sizes, int n_in,
                              void* d_out, int out_size, void* d_ws, size_t ws_size,
                              hipStream_t stream) {
  const float* x      = (const float*)d_in[0];
  const float* W_attn = (const float*)d_in[1];
  const float* b_attn = (const float*)d_in[2];
  const float* W_proj = (const float*)d_in[3];
  const float* b_proj = (const float*)d_in[4];
  float* out = (float*)d_out;
  char* ws = (char*)d_ws;

  const size_t SZ = 16777216;  // one [32,1024,256] bf16 buffer
  bf16* WT1 = (bf16*)(ws);                       // 768*512*2 = 786432
  bf16* WT2 = (bf16*)(ws + 786432);              // 512*256*2 = 262144
  bf16* qb  = (bf16*)(ws + 1048576);
  bf16* kb  = (bf16*)(ws + 1048576 + SZ);
  bf16* vb  = (bf16*)(ws + 1048576 + 2 * SZ);
  bf16* vtb = (bf16*)(ws + 1048576 + 3 * SZ);
  bf16* yb  = vb;  // v dead after transpose_v; reuse for y
  // xb [32768x512] bf16 = 32MB: aliases vtb slot + 16MB beyond.
  bf16* xbb = (bf16*)(ws + 1048576 + 3 * SZ);

  cvt_wattn<<<dim3(1536), dim3(256), 0, stream>>>(W_attn, WT1);
  cvt_wproj<<<dim3(512), dim3(256), 0, stream>>>(W_proj, WT2);
  cvt_x<<<dim3(8192), dim3(256), 0, stream>>>(x, xbb);
  gemm_qkv<<<dim3(1536), dim3(256), 0, stream>>>(xbb, WT1, b_attn, qb, kb, vb);
  transpose_v<<<dim3(32, 8, 32), dim3(256), 0, stream>>>(vb, vtb);
  attn_fwd<<<dim3(256), dim3(256), 0, stream>>>(qb, kb, vtb, yb);
  gemm_proj<<<dim3(1024), dim3(256), 0, stream>>>(yb, WT2, b_proj, out);
}

// Round 9
// 153.632 us; speedup vs baseline: 1.1157x; 1.1157x over previous
//
#include <hip/hip_runtime.h>
#include <hip/hip_bf16.h>
#include <math.h>

typedef __bf16 bf16;
typedef __attribute__((ext_vector_type(8))) __bf16 bf16x8;
typedef __attribute__((ext_vector_type(4))) __bf16 bf16x4;
typedef __attribute__((ext_vector_type(4))) float f32x4;

#define MFMA16(a, b, c) __builtin_amdgcn_mfma_f32_16x16x32_bf16((a), (b), (c), 0, 0, 0)

// Problem dims
// B=32, T=1024, VOCAB=512, RANK=256
// x [32768, 512] f32 ; W_attn [512,768] ; b_attn[768] ; W_proj [256,512] ; b_proj[512]

// ---------------- weight convert+transpose (tiny) ----------------
__global__ __launch_bounds__(256) void cvt_wattn(const float* __restrict__ w,
                                                 bf16* __restrict__ wt) {
  int o = blockIdx.x * 256 + threadIdx.x;   // 768*512 = 393216
  int n = o >> 9, kk = o & 511;
  wt[o] = (bf16)w[kk * 768 + n];            // WT[n][k] = W[k][n]
}

__global__ __launch_bounds__(256) void cvt_wproj(const float* __restrict__ w,
                                                 bf16* __restrict__ wt) {
  int o = blockIdx.x * 256 + threadIdx.x;   // 512*256 = 131072
  int n = o >> 8, kk = o & 255;
  wt[o] = (bf16)w[kk * 512 + n];            // WT[n][k] = W[k][n]
}

// ---------------- qkv GEMM: [32768,512]f32 x [768,512]^T ----------------
// v9: r5's reg-prefetch f32->bf16 staging (no cvt_x stream) + swapped MFMA
// (W on A side) -> bf16x4 vector epilogue. XCD-chunked linear grid.
__global__ __launch_bounds__(256) void gemm_qkv(
    const float* __restrict__ x, const bf16* __restrict__ WT,
    const float* __restrict__ b_attn,
    bf16* __restrict__ qo, bf16* __restrict__ ko, bf16* __restrict__ vo) {
  __shared__ __attribute__((aligned(16))) bf16 As[128][40];
  __shared__ __attribute__((aligned(16))) bf16 Bs[128][40];
  const int tid = threadIdx.x;
  // 1536 blocks: xcd = id&7 owns 192 = 32 M-panels x 6 N-blocks (N fastest)
  const int id = blockIdx.x;
  const int xcd = id & 7;
  const int rest = id >> 3;          // 0..191
  const int bmL = rest / 6;          // 0..31
  const int bn = (rest % 6) * 128;
  const int bm = (xcd * 32 + bmL) * 128;
  const int lane = tid & 63, wid = tid >> 6;
  const int l15 = lane & 15, lg = lane >> 4;
  const int wm = (wid >> 1) * 64, wn = (wid & 1) * 64;

  f32x4 acc[4][4] = {};

  const int srow = tid >> 1;
  const int scol = (tid & 1) * 16;
  const float* xp = x + (size_t)(bm + srow) * 512 + scol;
  const bf16* wp = WT + (size_t)(bn + srow) * 512 + scol;

  // T14 prologue: load + convert K-step 0 into regs
  bf16x8 ha[2], hb[2];
  {
    f32x4 f0 = *(const f32x4*)(xp);
    f32x4 f1 = *(const f32x4*)(xp + 4);
    f32x4 f2 = *(const f32x4*)(xp + 8);
    f32x4 f3 = *(const f32x4*)(xp + 12);
#pragma unroll
    for (int e = 0; e < 4; ++e) {
      ha[0][e] = (bf16)f0[e]; ha[0][e + 4] = (bf16)f1[e];
      ha[1][e] = (bf16)f2[e]; ha[1][e + 4] = (bf16)f3[e];
    }
    hb[0] = *(const bf16x8*)(wp);
    hb[1] = *(const bf16x8*)(wp + 8);
  }

  for (int kt = 0; kt < 16; ++kt) {
    __syncthreads();   // previous tile's LDS reads done
    *(bf16x8*)&As[srow][scol] = ha[0];
    *(bf16x8*)&As[srow][scol + 8] = ha[1];
    *(bf16x8*)&Bs[srow][scol] = hb[0];
    *(bf16x8*)&Bs[srow][scol + 8] = hb[1];
    __syncthreads();
    if (kt < 15) {     // prefetch next K-step; drains under the MFMAs below
      f32x4 f0 = *(const f32x4*)(xp + (kt + 1) * 32);
      f32x4 f1 = *(const f32x4*)(xp + (kt + 1) * 32 + 4);
      f32x4 f2 = *(const f32x4*)(xp + (kt + 1) * 32 + 8);
      f32x4 f3 = *(const f32x4*)(xp + (kt + 1) * 32 + 12);
#pragma unroll
      for (int e = 0; e < 4; ++e) {
        ha[0][e] = (bf16)f0[e]; ha[0][e + 4] = (bf16)f1[e];
        ha[1][e] = (bf16)f2[e]; ha[1][e + 4] = (bf16)f3[e];
      }
      hb[0] = *(const bf16x8*)(wp + (kt + 1) * 32);
      hb[1] = *(const bf16x8*)(wp + (kt + 1) * 32 + 8);
    }
    bf16x8 af[4], bfr[4];
#pragma unroll
    for (int mi = 0; mi < 4; ++mi)
      af[mi] = *(const bf16x8*)&As[wm + mi * 16 + l15][lg * 8];
#pragma unroll
    for (int ni = 0; ni < 4; ++ni)
      bfr[ni] = *(const bf16x8*)&Bs[wn + ni * 16 + l15][lg * 8];
    // swapped: A = W (N side in regs), B = x (M side on lanes)
    __builtin_amdgcn_s_setprio(1);
#pragma unroll
    for (int mi = 0; mi < 4; ++mi)
#pragma unroll
      for (int ni = 0; ni < 4; ++ni)
        acc[mi][ni] = MFMA16(bfr[ni], af[mi], acc[mi][ni]);
    __builtin_amdgcn_s_setprio(0);
  }

  // epilogue: row = bm+wm+mi*16+l15 (lane), cols = bn+wn+ni*16+lg*4+r (regs)
#pragma unroll
  for (int ni = 0; ni < 4; ++ni) {
    int gc0 = bn + wn + ni * 16 + lg * 4;
    f32x4 bias = *(const f32x4*)(b_attn + gc0);
    int seg = gc0 >> 8;        // 0=q 1=k 2=v (4-vector never crosses 256)
    int cc = gc0 & 255;
    bf16* op = (seg == 0) ? qo : ((seg == 1) ? ko : vo);
#pragma unroll
    for (int mi = 0; mi < 4; ++mi) {
      int gr = bm + wm + mi * 16 + l15;
      bf16x4 pk;
#pragma unroll
      for (int r = 0; r < 4; ++r) pk[r] = (bf16)(acc[mi][ni][r] + bias[r]);
      *(bf16x4*)(op + (size_t)gr * 256 + cc) = pk;
    }
  }
}

// ---------------- v -> v^T : [32][1024][256] -> [32][256][1024] ----------------
__global__ __launch_bounds__(256) void transpose_v(const bf16* __restrict__ v,
                                                   bf16* __restrict__ vt) {
  __shared__ bf16 tile[32][33];
  const int b = blockIdx.z;
  const int t0 = blockIdx.x * 32;
  const int d0 = blockIdx.y * 32;
  const int tid = threadIdx.x;
  const int r = tid >> 3, c4 = (tid & 7) * 4;
  bf16x4 in = *(const bf16x4*)(v + (size_t)(b * 1024 + t0 + r) * 256 + d0 + c4);
  tile[r][c4] = in[0]; tile[r][c4 + 1] = in[1];
  tile[r][c4 + 2] = in[2]; tile[r][c4 + 3] = in[3];
  __syncthreads();
  bf16x4 o;
  o[0] = tile[c4][r]; o[1] = tile[c4 + 1][r];
  o[2] = tile[c4 + 2][r]; o[3] = tile[c4 + 3][r];
  *(bf16x4*)(vt + (size_t)(b * 256 + d0 + r) * 1024 + t0 + c4) = o;
}

// ---------------- flash attention, causal, scale 1/16 (r7 v7, best) ----------------
// QBLK=128, 8 waves; K+Vt reg-staged into LDS (T14); swapped QK^T AND PV so
// softmax stats and O are lane-local (q = q0+l15); defer-max; vector y stores.
__global__ __launch_bounds__(512) void attn_fwd(
    const bf16* __restrict__ q, const bf16* __restrict__ k,
    const bf16* __restrict__ vt, bf16* __restrict__ y) {
  __shared__ __attribute__((aligned(16))) bf16 Ks[64][264];   // [s][d], +8 pad
  __shared__ __attribute__((aligned(16))) bf16 Vt[256][72];   // [d][s], +8 pad
  __shared__ __attribute__((aligned(16))) bf16 Ps[8][16][72]; // per-wave P [q][s]
  const int tid = threadIdx.x, lane = tid & 63, wid = tid >> 6;
  const int l15 = lane & 15, lg = lane >> 4;

  const int id = blockIdx.x;
  const int xcd = id & 7;
  const int rest = id >> 3;
  const int qt = rest & 7;         // q-tile of 128 rows
  const int bg = rest >> 3;
  const int b = xcd + 8 * bg;
  const int q0 = qt * 128 + wid * 16;

  bf16x8 qf[8];
  {
    const bf16* qp = q + (size_t)(b * 1024 + q0 + l15) * 256 + lg * 8;
#pragma unroll
    for (int d = 0; d < 8; ++d) qf[d] = *(const bf16x8*)(qp + d * 32);
  }
  f32x4 o[16] = {};   // o[df][r]: d = df*16 + lg*4 + r, q = q0 + l15
  float m_st = -1e30f;  // running max for q = q0+l15
  float l_st = 0.f;     // running denom for q = q0+l15

  const bf16* kbase = k + (size_t)b * 1024 * 256;
  const bf16* vtbase = vt + (size_t)b * 256 * 1024;
  const int ksr = tid >> 5, ksc = (tid & 31) * 8;   // K: 16 rows per iter
  const int vsr = tid >> 3, vsc = (tid & 7) * 8;    // Vt: 64 rows per iter

  const int ntiles = 2 * qt + 2;

  bf16x8 kreg[4], vreg[4];
#pragma unroll
  for (int i = 0; i < 4; ++i)
    kreg[i] = *(const bf16x8*)(kbase + (size_t)(ksr + i * 16) * 256 + ksc);
#pragma unroll
  for (int i = 0; i < 4; ++i)
    vreg[i] = *(const bf16x8*)(vtbase + (size_t)(vsr + i * 64) * 1024 + vsc);

  for (int tt = 0; tt < ntiles; ++tt) {
    const int kv0 = tt * 64;
    __syncthreads();
#pragma unroll
    for (int i = 0; i < 4; ++i)
      *(bf16x8*)&Ks[ksr + i * 16][ksc] = kreg[i];
#pragma unroll
    for (int i = 0; i < 4; ++i)
      *(bf16x8*)&Vt[vsr + i * 64][vsc] = vreg[i];
    __syncthreads();
    if (tt + 1 < ntiles) {
      const bf16* kp = kbase + (size_t)(kv0 + 64 + ksr) * 256 + ksc;
      const bf16* vp = vtbase + (size_t)vsr * 1024 + kv0 + 64 + vsc;
#pragma unroll
      for (int i = 0; i < 4; ++i)
        kreg[i] = *(const bf16x8*)(kp + (size_t)i * 16 * 256);
#pragma unroll
      for (int i = 0; i < 4; ++i)
        vreg[i] = *(const bf16x8*)(vp + (size_t)i * 64 * 1024);
    }

    // S^T = K Q^T : col = l15 = q, rows = s
    f32x4 st[4] = {};
    __builtin_amdgcn_s_setprio(1);
#pragma unroll
    for (int nf = 0; nf < 4; ++nf)
#pragma unroll
      for (int dc = 0; dc < 8; ++dc) {
        bf16x8 kb = *(const bf16x8*)&Ks[nf * 16 + l15][dc * 32 + lg * 8];
        st[nf] = MFMA16(kb, qf[dc], st[nf]);
      }
    __builtin_amdgcn_s_setprio(0);

    const int qg = q0 + l15;
    float tmax = -1e30f;
#pragma unroll
    for (int nf = 0; nf < 4; ++nf)
#pragma unroll
      for (int r = 0; r < 4; ++r) {
        int sg = kv0 + nf * 16 + lg * 4 + r;
        float v = st[nf][r] * 0.0625f;
        v = (sg > qg) ? -1e30f : v;
        st[nf][r] = v;
        tmax = fmaxf(tmax, v);
      }
    tmax = fmaxf(tmax, __shfl_xor(tmax, 16, 64));
    tmax = fmaxf(tmax, __shfl_xor(tmax, 32, 64));

    // defer-max: only rescale when the tile max grew past THR=8
    if (!__all(tmax <= m_st + 8.f)) {
      float mnew = fmaxf(m_st, tmax);
      float corr = __expf(m_st - mnew);
      m_st = mnew;
      l_st *= corr;
#pragma unroll
      for (int df = 0; df < 16; ++df)
#pragma unroll
        for (int r = 0; r < 4; ++r) o[df][r] *= corr;
    }

    // P = exp(S - m), row sum, pack bf16, write P[q][s] to per-wave LDS
    float rsum = 0.f;
#pragma unroll
    for (int nf = 0; nf < 4; ++nf) {
      bf16x4 pk;
#pragma unroll
      for (int r = 0; r < 4; ++r) {
        float p = __expf(st[nf][r] - m_st);
        rsum += p;
        pk[r] = (bf16)p;
      }
      *(bf16x4*)&Ps[wid][l15][nf * 16 + lg * 4] = pk;
    }
    rsum += __shfl_xor(rsum, 16, 64);
    rsum += __shfl_xor(rsum, 32, 64);
    l_st += rsum;

    // PV swapped: A = V^T rows (M=d in regs), B = P rows (N=q on lanes)
    bf16x8 pa0 = *(const bf16x8*)&Ps[wid][l15][lg * 8];
    bf16x8 pa1 = *(const bf16x8*)&Ps[wid][l15][32 + lg * 8];
    __builtin_amdgcn_s_setprio(1);
#pragma unroll
    for (int df = 0; df < 16; ++df) {
      bf16x8 vb0 = *(const bf16x8*)&Vt[df * 16 + l15][lg * 8];
      bf16x8 vb1 = *(const bf16x8*)&Vt[df * 16 + l15][32 + lg * 8];
      o[df] = MFMA16(vb0, pa0, o[df]);
      o[df] = MFMA16(vb1, pa1, o[df]);
    }
    __builtin_amdgcn_s_setprio(0);
  }

  // epilogue: all lane-local; vector stores along d
  float inv = 1.f / l_st;
  bf16* yp = y + (size_t)(b * 1024 + q0 + l15) * 256 + lg * 4;
#pragma unroll
  for (int df = 0; df < 16; ++df) {
    bf16x4 pk;
#pragma unroll
    for (int r = 0; r < 4; ++r) pk[r] = (bf16)(o[df][r] * inv);
    *(bf16x4*)(yp + df * 16) = pk;
  }
}

// ---------------- proj GEMM + bias + GELU (tanh form) ----------------
// v9: reg-staged bf16 with T14 prefetch + swapped MFMA -> f32x4 stores +
// overflow-safe tanh GELU. XCD-chunked linear grid.
__global__ __launch_bounds__(256) void gemm_proj(
    const bf16* __restrict__ y, const bf16* __restrict__ WT,
    const float* __restrict__ b_proj, float* __restrict__ out) {
  __shared__ __attribute__((aligned(16))) bf16 As[128][40];
  __shared__ __attribute__((aligned(16))) bf16 Bs[128][40];
  const int tid = threadIdx.x;
  // 1024 blocks: xcd owns 128 = 32 M-panels x 4 N-blocks (N fastest)
  const int id = blockIdx.x;
  const int xcd = id & 7;
  const int rest = id >> 3;          // 0..127
  const int bmL = rest >> 2;         // 0..31
  const int bn = (rest & 3) * 128;
  const int bm = (xcd * 32 + bmL) * 128;
  const int lane = tid & 63, wid = tid >> 6;
  const int l15 = lane & 15, lg = lane >> 4;
  const int wm = (wid >> 1) * 64, wn = (wid & 1) * 64;
  f32x4 acc[4][4] = {};

  const int srow = tid >> 1, scol = (tid & 1) * 16;
  const bf16* yp = y + (size_t)(bm + srow) * 256 + scol;
  const bf16* wp = WT + (size_t)(bn + srow) * 256 + scol;

  // T14 prologue
  bf16x8 ha[2], hb[2];
  ha[0] = *(const bf16x8*)(yp);
  ha[1] = *(const bf16x8*)(yp + 8);
  hb[0] = *(const bf16x8*)(wp);
  hb[1] = *(const bf16x8*)(wp + 8);

  for (int kt = 0; kt < 8; ++kt) {
    __syncthreads();
    *(bf16x8*)&As[srow][scol] = ha[0];  *(bf16x8*)&As[srow][scol + 8] = ha[1];
    *(bf16x8*)&Bs[srow][scol] = hb[0];  *(bf16x8*)&Bs[srow][scol + 8] = hb[1];
    __syncthreads();
    if (kt < 7) {
      ha[0] = *(const bf16x8*)(yp + (kt + 1) * 32);
      ha[1] = *(const bf16x8*)(yp + (kt + 1) * 32 + 8);
      hb[0] = *(const bf16x8*)(wp + (kt + 1) * 32);
      hb[1] = *(const bf16x8*)(wp + (kt + 1) * 32 + 8);
    }
    bf16x8 af[4], bfr[4];
#pragma unroll
    for (int mi = 0; mi < 4; ++mi)
      af[mi] = *(const bf16x8*)&As[wm + mi * 16 + l15][lg * 8];
#pragma unroll
    for (int ni = 0; ni < 4; ++ni)
      bfr[ni] = *(const bf16x8*)&Bs[wn + ni * 16 + l15][lg * 8];
    // swapped: A = W (N side in regs), B = y (M side on lanes)
    __builtin_amdgcn_s_setprio(1);
#pragma unroll
    for (int mi = 0; mi < 4; ++mi)
#pragma unroll
      for (int ni = 0; ni < 4; ++ni)
        acc[mi][ni] = MFMA16(bfr[ni], af[mi], acc[mi][ni]);
    __builtin_amdgcn_s_setprio(0);
  }

  // epilogue: row = bm+wm+mi*16+l15, cols = bn+wn+ni*16+lg*4 + r
#pragma unroll
  for (int ni = 0; ni < 4; ++ni) {
    int gc0 = bn + wn + ni * 16 + lg * 4;
    f32x4 bias = *(const f32x4*)(b_proj + gc0);
#pragma unroll
    for (int mi = 0; mi < 4; ++mi) {
      int gr = bm + wm + mi * 16 + l15;
      f32x4 g;
#pragma unroll
      for (int r = 0; r < 4; ++r) {
        float v = acc[mi][ni][r] + bias[r];
        float z = 1.5957691216f * (v + 0.044715f * v * v * v);
        float t = __expf(z);
        float th = 1.f - 2.f / (t + 1.f);   // tanh, overflow-safe
        g[r] = 0.5f * v * (1.f + th);
      }
      *(f32x4*)(out + (size_t)gr * 512 + gc0) = g;
    }
  }
}

extern "C" void kernel_launch(void* const* d_in, const int* in_sizes, int n_in,
                              void* d_out, int out_size, void* d_ws, size_t ws_size,
                              hipStream_t stream) {
  const float* x      = (const float*)d_in[0];
  const float* W_attn = (const float*)d_in[1];
  const float* b_attn = (const float*)d_in[2];
  const float* W_proj = (const float*)d_in[3];
  const float* b_proj = (const float*)d_in[4];
  float* out = (float*)d_out;
  char* ws = (char*)d_ws;

  const size_t SZ = 16777216;  // one [32,1024,256] bf16 buffer
  bf16* WT1 = (bf16*)(ws);                       // 768*512*2 = 786432
  bf16* WT2 = (bf16*)(ws + 786432);              // 512*256*2 = 262144
  bf16* qb  = (bf16*)(ws + 1048576);
  bf16* kb  = (bf16*)(ws + 1048576 + SZ);
  bf16* vb  = (bf16*)(ws + 1048576 + 2 * SZ);
  bf16* vtb = (bf16*)(ws + 1048576 + 3 * SZ);
  bf16* yb  = vb;  // v dead after transpose_v; reuse for y

  cvt_wattn<<<dim3(1536), dim3(256), 0, stream>>>(W_attn, WT1);
  cvt_wproj<<<dim3(512), dim3(256), 0, stream>>>(W_proj, WT2);
  gemm_qkv<<<dim3(1536), dim3(256), 0, stream>>>(x, WT1, b_attn, qb, kb, vb);
  transpose_v<<<dim3(32, 8, 32), dim3(256), 0, stream>>>(vb, vtb);
  attn_fwd<<<dim3(256), dim3(512), 0, stream>>>(qb, kb, vtb, yb);
  gemm_proj<<<dim3(1024), dim3(256), 0, stream>>>(yb, WT2, b_proj, out);
}

// Round 10
// 135.151 us; speedup vs baseline: 1.2683x; 1.1367x over previous
//
#include <hip/hip_runtime.h>
#include <hip/hip_bf16.h>
#include <math.h>

typedef __bf16 bf16;
typedef __attribute__((ext_vector_type(8))) __bf16 bf16x8;
typedef __attribute__((ext_vector_type(4))) __bf16 bf16x4;
typedef __attribute__((ext_vector_type(4))) float f32x4;

#define MFMA16(a, b, c) __builtin_amdgcn_mfma_f32_16x16x32_bf16((a), (b), (c), 0, 0, 0)

// Problem dims
// B=32, T=1024, VOCAB=512, RANK=256
// x [32768, 512] f32 ; W_attn [512,768] ; b_attn[768] ; W_proj [256,512] ; b_proj[512]

// ---------------- weight convert+transpose (tiny) ----------------
__global__ __launch_bounds__(256) void cvt_wattn(const float* __restrict__ w,
                                                 bf16* __restrict__ wt) {
  int o = blockIdx.x * 256 + threadIdx.x;   // 768*512 = 393216
  int n = o >> 9, kk = o & 511;
  wt[o] = (bf16)w[kk * 768 + n];            // WT[n][k] = W[k][n]
}

__global__ __launch_bounds__(256) void cvt_wproj(const float* __restrict__ w,
                                                 bf16* __restrict__ wt) {
  int o = blockIdx.x * 256 + threadIdx.x;   // 512*256 = 131072
  int n = o >> 8, kk = o & 255;
  wt[o] = (bf16)w[kk * 512 + n];            // WT[n][k] = W[k][n]
}

// ---------------- qkv GEMM: [32768,512]f32 x [768,512]^T ----------------
// v10: r9 structure + v written DIRECTLY TRANSPOSED (vt[b][d][t]) in the
// epilogue -> transpose_v kernel deleted. q/k unchanged (bf16x4 stores).
__global__ __launch_bounds__(256) void gemm_qkv(
    const float* __restrict__ x, const bf16* __restrict__ WT,
    const float* __restrict__ b_attn,
    bf16* __restrict__ qo, bf16* __restrict__ ko, bf16* __restrict__ vto) {
  __shared__ __attribute__((aligned(16))) bf16 As[128][40];
  __shared__ __attribute__((aligned(16))) bf16 Bs[128][40];
  const int tid = threadIdx.x;
  // 1536 blocks: xcd = id&7 owns 192 = 32 M-panels x 6 N-blocks (N fastest)
  const int id = blockIdx.x;
  const int xcd = id & 7;
  const int rest = id >> 3;          // 0..191
  const int bmL = rest / 6;          // 0..31
  const int bn = (rest % 6) * 128;
  const int bm = (xcd * 32 + bmL) * 128;
  const int lane = tid & 63, wid = tid >> 6;
  const int l15 = lane & 15, lg = lane >> 4;
  const int wm = (wid >> 1) * 64, wn = (wid & 1) * 64;

  f32x4 acc[4][4] = {};

  const int srow = tid >> 1;
  const int scol = (tid & 1) * 16;
  const float* xp = x + (size_t)(bm + srow) * 512 + scol;
  const bf16* wp = WT + (size_t)(bn + srow) * 512 + scol;

  // T14 prologue: load + convert K-step 0 into regs
  bf16x8 ha[2], hb[2];
  {
    f32x4 f0 = *(const f32x4*)(xp);
    f32x4 f1 = *(const f32x4*)(xp + 4);
    f32x4 f2 = *(const f32x4*)(xp + 8);
    f32x4 f3 = *(const f32x4*)(xp + 12);
#pragma unroll
    for (int e = 0; e < 4; ++e) {
      ha[0][e] = (bf16)f0[e]; ha[0][e + 4] = (bf16)f1[e];
      ha[1][e] = (bf16)f2[e]; ha[1][e + 4] = (bf16)f3[e];
    }
    hb[0] = *(const bf16x8*)(wp);
    hb[1] = *(const bf16x8*)(wp + 8);
  }

  for (int kt = 0; kt < 16; ++kt) {
    __syncthreads();   // previous tile's LDS reads done
    *(bf16x8*)&As[srow][scol] = ha[0];
    *(bf16x8*)&As[srow][scol + 8] = ha[1];
    *(bf16x8*)&Bs[srow][scol] = hb[0];
    *(bf16x8*)&Bs[srow][scol + 8] = hb[1];
    __syncthreads();
    if (kt < 15) {     // prefetch next K-step; drains under the MFMAs below
      f32x4 f0 = *(const f32x4*)(xp + (kt + 1) * 32);
      f32x4 f1 = *(const f32x4*)(xp + (kt + 1) * 32 + 4);
      f32x4 f2 = *(const f32x4*)(xp + (kt + 1) * 32 + 8);
      f32x4 f3 = *(const f32x4*)(xp + (kt + 1) * 32 + 12);
#pragma unroll
      for (int e = 0; e < 4; ++e) {
        ha[0][e] = (bf16)f0[e]; ha[0][e + 4] = (bf16)f1[e];
        ha[1][e] = (bf16)f2[e]; ha[1][e + 4] = (bf16)f3[e];
      }
      hb[0] = *(const bf16x8*)(wp + (kt + 1) * 32);
      hb[1] = *(const bf16x8*)(wp + (kt + 1) * 32 + 8);
    }
    bf16x8 af[4], bfr[4];
#pragma unroll
    for (int mi = 0; mi < 4; ++mi)
      af[mi] = *(const bf16x8*)&As[wm + mi * 16 + l15][lg * 8];
#pragma unroll
    for (int ni = 0; ni < 4; ++ni)
      bfr[ni] = *(const bf16x8*)&Bs[wn + ni * 16 + l15][lg * 8];
    // swapped: A = W (N side in regs), B = x (M side on lanes)
    __builtin_amdgcn_s_setprio(1);
#pragma unroll
    for (int mi = 0; mi < 4; ++mi)
#pragma unroll
      for (int ni = 0; ni < 4; ++ni)
        acc[mi][ni] = MFMA16(bfr[ni], af[mi], acc[mi][ni]);
    __builtin_amdgcn_s_setprio(0);
  }

  // epilogue: row = bm+wm+mi*16+l15 (lane), cols = bn+wn+ni*16+lg*4+r (regs)
  // seg is block-uniform (bn fixed): 0=q 1=k -> row-major [t][d];
  // 2=v -> store TRANSPOSED to vt[b][d][t] (lanes = consecutive t, coalesced)
#pragma unroll
  for (int ni = 0; ni < 4; ++ni) {
    int gc0 = bn + wn + ni * 16 + lg * 4;
    f32x4 bias = *(const f32x4*)(b_attn + gc0);
    int seg = gc0 >> 8;
    int cc = gc0 & 255;
    if (seg == 2) {
#pragma unroll
      for (int mi = 0; mi < 4; ++mi) {
        int gr = bm + wm + mi * 16 + l15;
        bf16* vp = vto + (size_t)(gr >> 10) * 262144 + (size_t)cc * 1024 + (gr & 1023);
#pragma unroll
        for (int r = 0; r < 4; ++r)
          vp[(size_t)r * 1024] = (bf16)(acc[mi][ni][r] + bias[r]);
      }
    } else {
      bf16* op = (seg == 0) ? qo : ko;
#pragma unroll
      for (int mi = 0; mi < 4; ++mi) {
        int gr = bm + wm + mi * 16 + l15;
        bf16x4 pk;
#pragma unroll
        for (int r = 0; r < 4; ++r) pk[r] = (bf16)(acc[mi][ni][r] + bias[r]);
        *(bf16x4*)(op + (size_t)gr * 256 + cc) = pk;
      }
    }
  }
}

// ---------------- flash attention, causal, scale 1/16 ----------------
// v10: QBLK=64, 4 waves, 512 blocks -> 2 blocks/CU (LDS 72KB, XOR-swizzled,
// no pads). Complementary tile pairing: ids u and u+32 get qt and 15-qt so
// each CU's two resident blocks sum to ~17 tile-steps (tail balance) and
// their independent barrier chains overlap staging with compute.
// Per-tile machinery = v7 (swapped QK^T + swapped PV, lane-local softmax).
__global__ __launch_bounds__(256) void attn_fwd(
    const bf16* __restrict__ q, const bf16* __restrict__ k,
    const bf16* __restrict__ vt, bf16* __restrict__ y) {
  __shared__ __attribute__((aligned(16))) bf16 Ks[64 * 256];    // 32KB, 512B rows, swz
  __shared__ __attribute__((aligned(16))) bf16 Vt[256 * 64];    // 32KB, 128B rows, swz
  __shared__ __attribute__((aligned(16))) bf16 Ps[4 * 16 * 64]; // 8KB per-wave P, swz
  const int tid = threadIdx.x, lane = tid & 63, wid = tid >> 6;
  const int l15 = lane & 15, lg = lane >> 4;

  // 512 blocks: id = xcd + 8*u, u = bg + 4*j (j=0..15); batch = xcd + 8*bg
  const int id = blockIdx.x;
  const int xcd = id & 7, u = id >> 3;
  const int bg = u & 3, j = u >> 2;
  const int b = xcd + 8 * bg;
  const int qt = (j < 8) ? j : 23 - j;   // u and u+32 -> qt and 15-qt
  const int q0 = qt * 64 + wid * 16;

  bf16x8 qf[8];
  {
    const bf16* qp = q + (size_t)(b * 1024 + q0 + l15) * 256 + lg * 8;
#pragma unroll
    for (int d = 0; d < 8; ++d) qf[d] = *(const bf16x8*)(qp + d * 32);
  }
  f32x4 o[16] = {};     // o[df][r]: d = df*16 + lg*4 + r, q = q0 + l15
  float m_st = -1e30f;  // running max for q = q0+l15
  float l_st = 0.f;     // running denom

  const char* kbase = (const char*)(k + (size_t)b * 262144);
  const char* vtbase = (const char*)(vt + (size_t)b * 262144);
  // staging maps (256 threads, 16B/thread/chunk); XOR key uniform per thread
  const int ksr = tid >> 5;            // K rows ksr + i*8
  const int kscb = (tid & 31) * 16;    // byte col in 512B row
  const int kkey = ksr << 4;           // (row&7)<<4, row&7 == ksr
  const int vsr = tid >> 3;            // Vt rows vsr + i*32
  const int vscb = (tid & 7) * 16;     // byte col in 128B row
  const int vkey = (vsr & 7) << 4;
  const int rkey = (l15 & 7) << 4;     // read-side key (rows indexed by l15)

  const int ntiles = qt + 1;

  bf16x8 kreg[8], vreg[8];
#pragma unroll
  for (int i = 0; i < 8; ++i)
    kreg[i] = *(const bf16x8*)(kbase + (size_t)(ksr + i * 8) * 512 + kscb);
#pragma unroll
  for (int i = 0; i < 8; ++i)
    vreg[i] = *(const bf16x8*)(vtbase + (size_t)(vsr + i * 32) * 2048 + vscb);

  for (int tt = 0; tt < ntiles; ++tt) {
    const int kv0 = tt * 64;
    __syncthreads();   // all waves done reading Ks/Vt (previous tile)
#pragma unroll
    for (int i = 0; i < 8; ++i)
      *(bf16x8*)((char*)Ks + (size_t)(ksr + i * 8) * 512 + (kscb ^ kkey)) = kreg[i];
#pragma unroll
    for (int i = 0; i < 8; ++i)
      *(bf16x8*)((char*)Vt + (size_t)(vsr + i * 32) * 128 + (vscb ^ vkey)) = vreg[i];
    __syncthreads();
    if (tt + 1 < ntiles) {   // next tile's loads drain under compute below
      const char* kp = kbase + (size_t)(kv0 + 64) * 512;
      const char* vp = vtbase + (size_t)(kv0 + 64) * 2;
#pragma unroll
      for (int i = 0; i < 8; ++i)
        kreg[i] = *(const bf16x8*)(kp + (size_t)(ksr + i * 8) * 512 + kscb);
#pragma unroll
      for (int i = 0; i < 8; ++i)
        vreg[i] = *(const bf16x8*)(vp + (size_t)(vsr + i * 32) * 2048 + vscb);
    }

    // S^T = K Q^T : col = l15 = q, rows = s (swizzled Ks reads)
    f32x4 st[4] = {};
    __builtin_amdgcn_s_setprio(1);
#pragma unroll
    for (int nf = 0; nf < 4; ++nf) {
      const char* rp = (const char*)Ks + (size_t)(nf * 16 + l15) * 512;
#pragma unroll
      for (int dc = 0; dc < 8; ++dc) {
        bf16x8 kb = *(const bf16x8*)(rp + ((dc * 64 + lg * 16) ^ rkey));
        st[nf] = MFMA16(kb, qf[dc], st[nf]);
      }
    }
    __builtin_amdgcn_s_setprio(0);

    const int qg = q0 + l15;
    float tmax = -1e30f;
#pragma unroll
    for (int nf = 0; nf < 4; ++nf)
#pragma unroll
      for (int r = 0; r < 4; ++r) {
        int sg = kv0 + nf * 16 + lg * 4 + r;
        float v = st[nf][r] * 0.0625f;
        v = (sg > qg) ? -1e30f : v;
        st[nf][r] = v;
        tmax = fmaxf(tmax, v);
      }
    tmax = fmaxf(tmax, __shfl_xor(tmax, 16, 64));
    tmax = fmaxf(tmax, __shfl_xor(tmax, 32, 64));

    // defer-max: only rescale when the tile max grew past THR=8
    if (!__all(tmax <= m_st + 8.f)) {
      float mnew = fmaxf(m_st, tmax);
      float corr = __expf(m_st - mnew);
      m_st = mnew;
      l_st *= corr;
#pragma unroll
      for (int df = 0; df < 16; ++df)
#pragma unroll
        for (int r = 0; r < 4; ++r) o[df][r] *= corr;
    }

    // P = exp(S - m), row sum, pack bf16, write P[q][s] (swizzled per-wave)
    char* psw = (char*)Ps + wid * 2048 + l15 * 128;
    float rsum = 0.f;
#pragma unroll
    for (int nf = 0; nf < 4; ++nf) {
      bf16x4 pk;
#pragma unroll
      for (int r = 0; r < 4; ++r) {
        float p = __expf(st[nf][r] - m_st);
        rsum += p;
        pk[r] = (bf16)p;
      }
      *(bf16x4*)(psw + ((nf * 32 + lg * 8) ^ rkey)) = pk;
    }
    rsum += __shfl_xor(rsum, 16, 64);
    rsum += __shfl_xor(rsum, 32, 64);
    l_st += rsum;

    // PV swapped: A = V^T rows (M=d in regs), B = P rows (N=q on lanes)
    bf16x8 pa0 = *(const bf16x8*)(psw + ((lg * 16) ^ rkey));
    bf16x8 pa1 = *(const bf16x8*)(psw + ((64 + lg * 16) ^ rkey));
    __builtin_amdgcn_s_setprio(1);
#pragma unroll
    for (int df = 0; df < 16; ++df) {
      const char* rp = (const char*)Vt + (size_t)(df * 16 + l15) * 128;
      bf16x8 vb0 = *(const bf16x8*)(rp + ((lg * 16) ^ rkey));
      bf16x8 vb1 = *(const bf16x8*)(rp + ((64 + lg * 16) ^ rkey));
      o[df] = MFMA16(vb0, pa0, o[df]);
      o[df] = MFMA16(vb1, pa1, o[df]);
    }
    __builtin_amdgcn_s_setprio(0);
  }

  // epilogue: all lane-local; vector stores along d
  float inv = 1.f / l_st;
  bf16* yp = y + (size_t)(b * 1024 + q0 + l15) * 256 + lg * 4;
#pragma unroll
  for (int df = 0; df < 16; ++df) {
    bf16x4 pk;
#pragma unroll
    for (int r = 0; r < 4; ++r) pk[r] = (bf16)(o[df][r] * inv);
    *(bf16x4*)(yp + df * 16) = pk;
  }
}

// ---------------- proj GEMM + bias + GELU (tanh form) ----------------
// v9: reg-staged bf16 with T14 prefetch + swapped MFMA -> f32x4 stores +
// overflow-safe tanh GELU. XCD-chunked linear grid.
__global__ __launch_bounds__(256) void gemm_proj(
    const bf16* __restrict__ y, const bf16* __restrict__ WT,
    const float* __restrict__ b_proj, float* __restrict__ out) {
  __shared__ __attribute__((aligned(16))) bf16 As[128][40];
  __shared__ __attribute__((aligned(16))) bf16 Bs[128][40];
  const int tid = threadIdx.x;
  const int id = blockIdx.x;
  const int xcd = id & 7;
  const int rest = id >> 3;          // 0..127
  const int bmL = rest >> 2;         // 0..31
  const int bn = (rest & 3) * 128;
  const int bm = (xcd * 32 + bmL) * 128;
  const int lane = tid & 63, wid = tid >> 6;
  const int l15 = lane & 15, lg = lane >> 4;
  const int wm = (wid >> 1) * 64, wn = (wid & 1) * 64;
  f32x4 acc[4][4] = {};

  const int srow = tid >> 1, scol = (tid & 1) * 16;
  const bf16* yp = y + (size_t)(bm + srow) * 256 + scol;
  const bf16* wp = WT + (size_t)(bn + srow) * 256 + scol;

  bf16x8 ha[2], hb[2];
  ha[0] = *(const bf16x8*)(yp);
  ha[1] = *(const bf16x8*)(yp + 8);
  hb[0] = *(const bf16x8*)(wp);
  hb[1] = *(const bf16x8*)(wp + 8);

  for (int kt = 0; kt < 8; ++kt) {
    __syncthreads();
    *(bf16x8*)&As[srow][scol] = ha[0];  *(bf16x8*)&As[srow][scol + 8] = ha[1];
    *(bf16x8*)&Bs[srow][scol] = hb[0];  *(bf16x8*)&Bs[srow][scol + 8] = hb[1];
    __syncthreads();
    if (kt < 7) {
      ha[0] = *(const bf16x8*)(yp + (kt + 1) * 32);
      ha[1] = *(const bf16x8*)(yp + (kt + 1) * 32 + 8);
      hb[0] = *(const bf16x8*)(wp + (kt + 1) * 32);
      hb[1] = *(const bf16x8*)(wp + (kt + 1) * 32 + 8);
    }
    bf16x8 af[4], bfr[4];
#pragma unroll
    for (int mi = 0; mi < 4; ++mi)
      af[mi] = *(const bf16x8*)&As[wm + mi * 16 + l15][lg * 8];
#pragma unroll
    for (int ni = 0; ni < 4; ++ni)
      bfr[ni] = *(const bf16x8*)&Bs[wn + ni * 16 + l15][lg * 8];
    __builtin_amdgcn_s_setprio(1);
#pragma unroll
    for (int mi = 0; mi < 4; ++mi)
#pragma unroll
      for (int ni = 0; ni < 4; ++ni)
        acc[mi][ni] = MFMA16(bfr[ni], af[mi], acc[mi][ni]);
    __builtin_amdgcn_s_setprio(0);
  }

#pragma unroll
  for (int ni = 0; ni < 4; ++ni) {
    int gc0 = bn + wn + ni * 16 + lg * 4;
    f32x4 bias = *(const f32x4*)(b_proj + gc0);
#pragma unroll
    for (int mi = 0; mi < 4; ++mi) {
      int gr = bm + wm + mi * 16 + l15;
      f32x4 g;
#pragma unroll
      for (int r = 0; r < 4; ++r) {
        float v = acc[mi][ni][r] + bias[r];
        float z = 1.5957691216f * (v + 0.044715f * v * v * v);
        float t = __expf(z);
        float th = 1.f - 2.f / (t + 1.f);   // tanh, overflow-safe
        g[r] = 0.5f * v * (1.f + th);
      }
      *(f32x4*)(out + (size_t)gr * 512 + gc0) = g;
    }
  }
}

extern "C" void kernel_launch(void* const* d_in, const int* in_sizes, int n_in,
                              void* d_out, int out_size, void* d_ws, size_t ws_size,
                              hipStream_t stream) {
  const float* x      = (const float*)d_in[0];
  const float* W_attn = (const float*)d_in[1];
  const float* b_attn = (const float*)d_in[2];
  const float* W_proj = (const float*)d_in[3];
  const float* b_proj = (const float*)d_in[4];
  float* out = (float*)d_out;
  char* ws = (char*)d_ws;

  const size_t SZ = 16777216;  // one [32,1024,256] bf16 buffer
  bf16* WT1 = (bf16*)(ws);                       // 768*512*2 = 786432
  bf16* WT2 = (bf16*)(ws + 786432);              // 512*256*2 = 262144
  bf16* qb  = (bf16*)(ws + 1048576);
  bf16* kb  = (bf16*)(ws + 1048576 + SZ);
  bf16* vtb = (bf16*)(ws + 1048576 + 2 * SZ);    // v written transposed by qkv
  bf16* yb  = (bf16*)(ws + 1048576 + 3 * SZ);

  cvt_wattn<<<dim3(1536), dim3(256), 0, stream>>>(W_attn, WT1);
  cvt_wproj<<<dim3(512), dim3(256), 0, stream>>>(W_proj, WT2);
  gemm_qkv<<<dim3(1536), dim3(256), 0, stream>>>(x, WT1, b_attn, qb, kb, vtb);
  attn_fwd<<<dim3(512), dim3(256), 0, stream>>>(qb, kb, vtb, yb);
  gemm_proj<<<dim3(1024), dim3(256), 0, stream>>>(yb, WT2, b_proj, out);
}